// Round 4
// baseline (67.724 us; speedup 1.0000x reference)
//
#include <hip/hip_runtime.h>

// L2-distance causal attention with zero-KV sink.
// B=2, H=16, N=2048, D=64. fp32 in/out, bf16 MFMA internally.
//
// Structure:
//   Kernel 1 (build_ws): one-shot conversion of K/V into per-64-key-tile LDS
//     byte images (bf16, slot-permuted + XOR-swizzled K; transposed+swizzled
//     V^T) plus per-key bias -BS*|k_bf|^2, in d_ws.
//   Kernel 2 (attend): flash loop. Round 4:
//     - KVBLK=128 per iteration (two 64-key halves => 2 independent softmax
//       chains for ILP, half the barriers/loop overhead per unit work)
//     - complementary query-tile pairing: block handles qt=pq and qt=31-pq;
//       every block does exactly 17 iterations => 512 uniform blocks,
//       2 blocks/CU constant, zero tail. bh in low bits => per-head ws slice
//       pinned to one XCD's L2.
//     - s_setprio(1) around MFMA clusters (T5).

#define NQ 2048
#define DH 64
#define NT 32   // 64-key tiles per sequence

typedef float f32x4 __attribute__((ext_vector_type(4)));
typedef __bf16 bf16x8 __attribute__((ext_vector_type(8)));
typedef unsigned short u16x8 __attribute__((ext_vector_type(8)));

union B8 { u16x8 u; bf16x8 b; };

__device__ __forceinline__ unsigned short f2b(float f) {
  unsigned int x = __builtin_bit_cast(unsigned int, f);
  unsigned int r = x + 0x7fffu + ((x >> 16) & 1u);   // RNE to bf16
  return (unsigned short)(r >> 16);
}
__device__ __forceinline__ float b2f(unsigned short u) {
  unsigned int t = ((unsigned int)u) << 16;
  return __builtin_bit_cast(float, t);
}
__device__ __forceinline__ f32x4 vmax4(f32x4 a, f32x4 b) {
  f32x4 r;
  r[0] = fmaxf(a[0], b[0]); r[1] = fmaxf(a[1], b[1]);
  r[2] = fmaxf(a[2], b[2]); r[3] = fmaxf(a[3], b[3]);
  return r;
}

// K-slot permutation: slot s (bits c1 c0 g1 g0 r1 r0) holds key (c1 g1 g0 c0 r1 r0).
// Makes QK^T's C-layout scores be exactly the PV B-fragment values (no exchange).
__device__ __forceinline__ int kslot(int a) {
  return (a & 0x23) | ((a & 0x04) << 2) | ((a & 0x18) >> 1);
}

__device__ __forceinline__ void gl_lds16(const void* g, void* l) {
  __builtin_amdgcn_global_load_lds(
      (const __attribute__((address_space(1))) unsigned int*)g,
      (__attribute__((address_space(3))) unsigned int*)l, 16, 0, 0);
}

constexpr float QS = 0.3551784733906239f;   // 2*log2(e)/sqrt(66)
constexpr float BS = 0.17758923669531197f;  // log2(e)/sqrt(66)

// ---------------- kernel 1: build per-tile images ----------------
__global__ __launch_bounds__(256) void build_ws(
    const float* __restrict__ k, const float* __restrict__ v,
    unsigned short* __restrict__ wsK, unsigned short* __restrict__ wsV,
    float* __restrict__ wsB)
{
  const int bh = blockIdx.x;          // 0..31
  const int t  = blockIdx.y;          // 0..31
  const int tid  = threadIdx.x;
  const int wid  = tid >> 6;
  const int lane = tid & 63;
  const size_t bhN = (size_t)bh * NQ;
  const int tile64 = t * 64;
  const size_t tileId = (size_t)bh * NT + t;
  unsigned short* Kt = wsK + tileId * 4096;
  unsigned short* Vt = wsV + tileId * 4096;
  float*          Bt = wsB + tileId * 64;

  // K image (+ bias), slot-permuted, XOR-swizzled — exact LDS byte image.
#pragma unroll
  for (int i = 0; i < 4; i++) {
    int f  = i * 256 + tid;
    int kg = f >> 4, d4 = f & 15;
    int slot = kslot(kg);
    const float4* kp = (const float4*)(k + (bhN + tile64 + kg) * DH);
    float4 kk = kp[d4];
    unsigned short h0 = f2b(kk.x), h1 = f2b(kk.y), h2 = f2b(kk.z), h3 = f2b(kk.w);
    float a0 = b2f(h0), a1 = b2f(h1), a2 = b2f(h2), a3 = b2f(h3);
    float ss = a0*a0 + a1*a1 + a2*a2 + a3*a3;     // |k_bf|^2 partial
    ss += __shfl_xor(ss, 1, 64);
    ss += __shfl_xor(ss, 2, 64);
    ss += __shfl_xor(ss, 4, 64);
    ss += __shfl_xor(ss, 8, 64);
    if (d4 == 0) Bt[slot] = -BS * ss;
    unsigned int w0 = (unsigned int)h0 | ((unsigned int)h1 << 16);
    unsigned int w1 = (unsigned int)h2 | ((unsigned int)h3 << 16);
    int idx = slot * 64 + ((d4 * 4) ^ ((slot & 7) << 3));
    uint2 wv; wv.x = w0; wv.y = w1;
    *(uint2*)&Kt[idx] = wv;
  }

  // V^T image (identity slot order), XOR-swizzled.
#pragma unroll
  for (int jj = 0; jj < 4; jj++) {
    int kgb = jj * 16 + wid * 4;
    const float* vp = v + (bhN + tile64 + kgb) * DH + lane;
    float x0 = vp[0], x1 = vp[DH], x2 = vp[2 * DH], x3 = vp[3 * DH];
    unsigned int w0 = (unsigned int)f2b(x0) | ((unsigned int)f2b(x1) << 16);
    unsigned int w1 = (unsigned int)f2b(x2) | ((unsigned int)f2b(x3) << 16);
    int idx = lane * 64 + (kgb ^ ((lane & 7) << 3));
    uint2 wv; wv.x = w0; wv.y = w1;
    *(uint2*)&Vt[idx] = wv;
  }
}

// ---------------- kernel 2: flash attention over premade images ----------------
__global__ __launch_bounds__(256) void attend_l2_flash(
    const float* __restrict__ q,
    const unsigned short* __restrict__ wsK,
    const unsigned short* __restrict__ wsV,
    const float* __restrict__ wsB,
    float* __restrict__ out)
{
  const int bid  = blockIdx.x;        // 512 blocks
  const int bh   = bid & 31;          // low bits => same head pinned to one XCD
  const int pq   = bid >> 5;          // 0..15
  const int tid  = threadIdx.x;
  const int wid  = tid >> 6;
  const int lane = tid & 63;
  const int g    = lane >> 4;
  const int qi   = lane & 15;
  const size_t bhN   = (size_t)bh * NQ;
  const size_t tbase = (size_t)bh * NT;

  __shared__ __align__(16) unsigned short sK[2][8192]; // [buf][half*4096 + slot*64 + swz d]
  __shared__ __align__(16) unsigned short sV[2][8192];
  __shared__ __align__(16) float sB[2][128];

  // stage 128-key iter `it` (ws tiles 2it, 2it+1 = contiguous 16KB) into buf
  auto STAGE = [&](int buf, int it) {
    const char* Kt = (const char*)(wsK + (tbase + (size_t)it * 2) * 4096);
    const char* Vt = (const char*)(wsV + (tbase + (size_t)it * 2) * 4096);
#pragma unroll
    for (int cc = 0; cc < 4; cc++) {
      int boff = wid * 4096 + cc * 1024;
      gl_lds16(Kt + boff + lane * 16, (char*)&sK[buf][0] + boff);
      gl_lds16(Vt + boff + lane * 16, (char*)&sV[buf][0] + boff);
    }
    if (tid < 32) {
      const char* Bt = (const char*)(wsB + (tbase + (size_t)it * 2) * 64);
      gl_lds16(Bt + tid * 16, (char*)&sB[buf][0] + tid * 16);
    }
  };

#pragma unroll 1
  for (int seg = 0; seg < 2; seg++) {
    const int qt = seg ? (31 - pq) : pq;
    const int qg = qt * 64 + wid * 16 + qi;        // this lane's query row
    const int nIt = (qt + 2) >> 1;                 // ceil((qt+1)/2); A+B = 17

    // ---- Q fragments (hi/lo split) ----
    const float* qrow = q + (bhN + qg) * DH;
    bf16x8 qhi[2], qlo[2];
#pragma unroll
    for (int ks = 0; ks < 2; ks++) {
      B8 th, tl;
#pragma unroll
      for (int j = 0; j < 8; j++) {
        float x = qrow[ks * 32 + g * 8 + j] * QS;
        unsigned short h = f2b(x);
        th.u[j] = h;
        tl.u[j] = f2b(x - b2f(h));
      }
      qhi[ks] = th.b; qlo[ks] = tl.b;
    }

    f32x4 oacc[4] = { {0,0,0,0}, {0,0,0,0}, {0,0,0,0}, {0,0,0,0} };
    float m = 0.0f;                 // running max (base-2; sink pins m >= 0)
    f32x4 l4 = {0, 0, 0, 0};        // packed partial denominator

    int cur = 0;
    STAGE(0, 0);
    __syncthreads();

    for (int it = 0; it < nIt; it++) {
      if (it + 1 < nIt) STAGE(cur ^ 1, it + 1);

      // ---- QK^T, swapped: S^T = K . Q^T  (two independent 64-key halves) ----
      f32x4 sc[2][4] = {{{0,0,0,0},{0,0,0,0},{0,0,0,0},{0,0,0,0}},
                        {{0,0,0,0},{0,0,0,0},{0,0,0,0},{0,0,0,0}}};
      __builtin_amdgcn_s_setprio(1);
#pragma unroll
      for (int h = 0; h < 2; h++) {
#pragma unroll
        for (int c = 0; c < 4; c++) {
#pragma unroll
          for (int ks = 0; ks < 2; ks++) {
            int idx = h * 4096 + (16 * c + qi) * 64 + ((ks * 32 + g * 8) ^ ((qi & 7) << 3));
            bf16x8 ak = *(const bf16x8*)&sK[cur][idx];
            sc[h][c] = __builtin_amdgcn_mfma_f32_16x16x32_bf16(ak, qhi[ks], sc[h][c], 0, 0, 0);
            sc[h][c] = __builtin_amdgcn_mfma_f32_16x16x32_bf16(ak, qlo[ks], sc[h][c], 0, 0, 0);
          }
        }
      }
      __builtin_amdgcn_s_setprio(0);

      // ---- softmax: s = sc + bias, causal mask on the final iteration ----
      const bool diag = (it == nIt - 1);
      const int base128 = it * 128;
#pragma unroll
      for (int h = 0; h < 2; h++) {
#pragma unroll
        for (int c = 0; c < 4; c++) {
          f32x4 bb = *(const f32x4*)&sB[cur][h * 64 + 16 * c + 4 * g];
          sc[h][c] += bb;                          // v_pk_add_f32
          if (diag) {
#pragma unroll
            for (int r = 0; r < 4; r++) {
              int key = base128 + h * 64 + 32 * (c >> 1) + 8 * g + 4 * (c & 1) + r;
              if (key > qg) sc[h][c][r] = -1e30f;
            }
          }
        }
      }

      // ---- exact defer-max: rescale only if some score exceeds running max ----
      f32x4 mv = vmax4(vmax4(vmax4(sc[0][0], sc[0][1]), vmax4(sc[0][2], sc[0][3])),
                       vmax4(vmax4(sc[1][0], sc[1][1]), vmax4(sc[1][2], sc[1][3])));
      float mloc = fmaxf(fmaxf(fmaxf(mv[0], mv[1]), mv[2]), mv[3]);
      if (!__all(mloc <= m)) {                    // ~never taken (sink pins m=0)
        float mt = fmaxf(mloc, __shfl_xor(mloc, 16, 64));
        mt = fmaxf(mt, __shfl_xor(mt, 32, 64));
        float dm = fmaxf(mt - m, 0.0f);
        m += dm;
        float alpha = exp2f(-dm);
        l4 *= alpha;
#pragma unroll
        for (int db = 0; db < 4; db++) oacc[db] *= alpha;
      }

      // ---- weights: e = exp2(s - m); m==0 fast path (two independent chains) ----
      if (__all(m == 0.0f)) {
#pragma unroll
        for (int h = 0; h < 2; h++)
#pragma unroll
          for (int c = 0; c < 4; c++) {
#pragma unroll
            for (int r = 0; r < 4; r++) sc[h][c][r] = exp2f(sc[h][c][r]);
            l4 += sc[h][c];
          }
      } else {
#pragma unroll
        for (int h = 0; h < 2; h++)
#pragma unroll
          for (int c = 0; c < 4; c++) {
#pragma unroll
            for (int r = 0; r < 4; r++) sc[h][c][r] = exp2f(sc[h][c][r] - m);
            l4 += sc[h][c];
          }
      }

      // ---- P repack (local by slot-permutation construction) ----
      B8 pr[2][2];
#pragma unroll
      for (int h = 0; h < 2; h++)
#pragma unroll
        for (int j = 0; j < 8; j++) {
          pr[h][0].b[j] = (__bf16)sc[h][(j >> 2)][j & 3];
          pr[h][1].b[j] = (__bf16)sc[h][2 + (j >> 2)][j & 3];
        }

      // ---- PV: O^T += V^T . P^T (both halves) ----
      __builtin_amdgcn_s_setprio(1);
#pragma unroll
      for (int h = 0; h < 2; h++) {
#pragma unroll
        for (int db = 0; db < 4; db++) {
#pragma unroll
          for (int ks = 0; ks < 2; ks++) {
            int idx = h * 4096 + (db * 16 + qi) * 64 + ((ks * 32 + g * 8) ^ ((qi & 7) << 3));
            bf16x8 av = *(const bf16x8*)&sV[cur][idx];
            oacc[db] = __builtin_amdgcn_mfma_f32_16x16x32_bf16(av, pr[h][ks].b,
                                                               oacc[db], 0, 0, 0);
          }
        }
      }
      __builtin_amdgcn_s_setprio(0);
      __syncthreads();   // next tile landed + LDS reuse fence
      cur ^= 1;
    }

    // ---- epilogue ----
    float lt = (l4[0] + l4[1]) + (l4[2] + l4[3]);
    lt += __shfl_xor(lt, 16, 64);
    lt += __shfl_xor(lt, 32, 64);
    float denom = lt + exp2f(-m);   // + sink weight
    float inv = 1.0f / denom;
    float* op = out + (bhN + qg) * DH;
#pragma unroll
    for (int db = 0; db < 4; db++) {
      float4 o;
      o.x = oacc[db][0] * inv;
      o.y = oacc[db][1] * inv;
      o.z = oacc[db][2] * inv;
      o.w = oacc[db][3] * inv;
      *(float4*)(op + db * 16 + 4 * g) = o;
    }
  }
}

extern "C" void kernel_launch(void* const* d_in, const int* in_sizes, int n_in,
                              void* d_out, int out_size, void* d_ws, size_t ws_size,
                              hipStream_t stream) {
  (void)in_sizes; (void)n_in; (void)out_size; (void)ws_size;
  const float* q = (const float*)d_in[0];
  const float* k = (const float*)d_in[1];
  const float* v = (const float*)d_in[2];
  float* out = (float*)d_out;

  // ws layout: K images 8 MiB | V images 8 MiB | bias 256 KiB
  char* ws = (char*)d_ws;
  unsigned short* wsK = (unsigned short*)ws;
  unsigned short* wsV = (unsigned short*)(ws + (8u << 20));
  float*          wsB = (float*)(ws + (16u << 20));

  build_ws<<<dim3(32, NT), dim3(256), 0, stream>>>(k, v, wsK, wsV, wsB);
  attend_l2_flash<<<dim3(512), dim3(256), 0, stream>>>(q, wsK, wsV, wsB, out);
}

// Round 5
// 63.413 us; speedup vs baseline: 1.0680x; 1.0680x over previous
//
#include <hip/hip_runtime.h>

// L2-distance causal attention with zero-KV sink.
// B=2, H=16, N=2048, D=64. fp32 in/out, bf16 MFMA internally.
//
// Structure:
//   Kernel 1 (build_ws): one-shot conversion of K/V into per-64-key-tile LDS
//     byte images (bf16, slot-permuted + XOR-swizzled K; transposed+swizzled
//     V^T) plus per-key bias -BS*|k_bf|^2, in d_ws.
//   Kernel 2 (attend): flash loop, KVBLK=64, double-buffered global_load_lds
//     staging, in-register softmax (swapped QK^T + slot permutation).
//   Round 4: residency-balanced grid. 1024 blocks (4/CU, ALL resident from
//     t=0; LDS 33KB*4=133KB, VGPR 68 -> 16-wave cap). qt mapping chosen so
//     co-resident blocks (dispatch stride 256 ~ y+8) have qt {g,31-g,8+g,23-g}
//     => per-CU work == 66 tiles, constant. No setprio (null/negative here).

#define NQ 2048
#define DH 64
#define NT 32   // 64-key tiles per sequence

typedef float f32x4 __attribute__((ext_vector_type(4)));
typedef __bf16 bf16x8 __attribute__((ext_vector_type(8)));
typedef unsigned short u16x8 __attribute__((ext_vector_type(8)));

union B8 { u16x8 u; bf16x8 b; };

__device__ __forceinline__ unsigned short f2b(float f) {
  unsigned int x = __builtin_bit_cast(unsigned int, f);
  unsigned int r = x + 0x7fffu + ((x >> 16) & 1u);   // RNE to bf16
  return (unsigned short)(r >> 16);
}
__device__ __forceinline__ float b2f(unsigned short u) {
  unsigned int t = ((unsigned int)u) << 16;
  return __builtin_bit_cast(float, t);
}
__device__ __forceinline__ f32x4 vmax4(f32x4 a, f32x4 b) {
  f32x4 r;
  r[0] = fmaxf(a[0], b[0]); r[1] = fmaxf(a[1], b[1]);
  r[2] = fmaxf(a[2], b[2]); r[3] = fmaxf(a[3], b[3]);
  return r;
}

// K-slot permutation: slot s (bits c1 c0 g1 g0 r1 r0) holds key (c1 g1 g0 c0 r1 r0).
// Makes QK^T's C-layout scores be exactly the PV B-fragment values (no exchange).
__device__ __forceinline__ int kslot(int a) {
  return (a & 0x23) | ((a & 0x04) << 2) | ((a & 0x18) >> 1);
}

__device__ __forceinline__ void gl_lds16(const void* g, void* l) {
  __builtin_amdgcn_global_load_lds(
      (const __attribute__((address_space(1))) unsigned int*)g,
      (__attribute__((address_space(3))) unsigned int*)l, 16, 0, 0);
}
__device__ __forceinline__ void gl_lds4(const void* g, void* l) {
  __builtin_amdgcn_global_load_lds(
      (const __attribute__((address_space(1))) unsigned int*)g,
      (__attribute__((address_space(3))) unsigned int*)l, 4, 0, 0);
}

constexpr float QS = 0.3551784733906239f;   // 2*log2(e)/sqrt(66)
constexpr float BS = 0.17758923669531197f;  // log2(e)/sqrt(66)

// ---------------- kernel 1: build per-tile images ----------------
__global__ __launch_bounds__(256) void build_ws(
    const float* __restrict__ k, const float* __restrict__ v,
    unsigned short* __restrict__ wsK, unsigned short* __restrict__ wsV,
    float* __restrict__ wsB)
{
  const int bh = blockIdx.x;          // 0..31
  const int t  = blockIdx.y;          // 0..31
  const int tid  = threadIdx.x;
  const int wid  = tid >> 6;
  const int lane = tid & 63;
  const size_t bhN = (size_t)bh * NQ;
  const int tile64 = t * 64;
  const size_t tileId = (size_t)bh * NT + t;
  unsigned short* Kt = wsK + tileId * 4096;
  unsigned short* Vt = wsV + tileId * 4096;
  float*          Bt = wsB + tileId * 64;

  // K image (+ bias), slot-permuted, XOR-swizzled — exact LDS byte image.
#pragma unroll
  for (int i = 0; i < 4; i++) {
    int f  = i * 256 + tid;
    int kg = f >> 4, d4 = f & 15;
    int slot = kslot(kg);
    const float4* kp = (const float4*)(k + (bhN + tile64 + kg) * DH);
    float4 kk = kp[d4];
    unsigned short h0 = f2b(kk.x), h1 = f2b(kk.y), h2 = f2b(kk.z), h3 = f2b(kk.w);
    float a0 = b2f(h0), a1 = b2f(h1), a2 = b2f(h2), a3 = b2f(h3);
    float ss = a0*a0 + a1*a1 + a2*a2 + a3*a3;     // |k_bf|^2 partial
    ss += __shfl_xor(ss, 1, 64);
    ss += __shfl_xor(ss, 2, 64);
    ss += __shfl_xor(ss, 4, 64);
    ss += __shfl_xor(ss, 8, 64);
    if (d4 == 0) Bt[slot] = -BS * ss;
    unsigned int w0 = (unsigned int)h0 | ((unsigned int)h1 << 16);
    unsigned int w1 = (unsigned int)h2 | ((unsigned int)h3 << 16);
    int idx = slot * 64 + ((d4 * 4) ^ ((slot & 7) << 3));
    uint2 wv; wv.x = w0; wv.y = w1;
    *(uint2*)&Kt[idx] = wv;
  }

  // V^T image (identity slot order), XOR-swizzled.
#pragma unroll
  for (int jj = 0; jj < 4; jj++) {
    int kgb = jj * 16 + wid * 4;
    const float* vp = v + (bhN + tile64 + kgb) * DH + lane;
    float x0 = vp[0], x1 = vp[DH], x2 = vp[2 * DH], x3 = vp[3 * DH];
    unsigned int w0 = (unsigned int)f2b(x0) | ((unsigned int)f2b(x1) << 16);
    unsigned int w1 = (unsigned int)f2b(x2) | ((unsigned int)f2b(x3) << 16);
    int idx = lane * 64 + (kgb ^ ((lane & 7) << 3));
    uint2 wv; wv.x = w0; wv.y = w1;
    *(uint2*)&Vt[idx] = wv;
  }
}

// ---------------- kernel 2: flash attention over premade images ----------------
__global__ __launch_bounds__(256) void attend_l2_flash(
    const float* __restrict__ q,
    const unsigned short* __restrict__ wsK,
    const unsigned short* __restrict__ wsV,
    const float* __restrict__ wsB,
    float* __restrict__ out)
{
  const int b    = blockIdx.x;        // 1024 blocks, all resident (4/CU)
  const int bh   = b & 31;            // low bits => head pinned to one XCD's L2
  const int y    = b >> 5;            // 0..31
  const int g5   = y & 7;
  const int s    = y >> 3;            // co-resident blocks differ in s
  // qt in {g5, 31-g5, 8+g5, 23-g5}: per-CU sum of (qt+1) == 66, constant.
  const int qt   = (s == 0) ? g5 : (s == 1) ? (31 - g5) : (s == 2) ? (8 + g5) : (23 - g5);

  const int tid  = threadIdx.x;
  const int wid  = tid >> 6;
  const int lane = tid & 63;
  const int g    = lane >> 4;
  const int qi   = lane & 15;
  const int qg   = qt * 64 + wid * 16 + qi;        // this lane's query row
  const size_t bhN = (size_t)bh * NQ;

  __shared__ __align__(16) unsigned short sK[2][4096];
  __shared__ __align__(16) unsigned short sV[2][4096];
  __shared__ __align__(16) float sB[2][64];

  // ---- Q fragments (hi/lo split), hoisted ----
  const float* qrow = q + (bhN + qg) * DH;
  bf16x8 qhi[2], qlo[2];
#pragma unroll
  for (int ks = 0; ks < 2; ks++) {
    B8 th, tl;
#pragma unroll
    for (int j = 0; j < 8; j++) {
      float x = qrow[ks * 32 + g * 8 + j] * QS;
      unsigned short h = f2b(x);
      th.u[j] = h;
      tl.u[j] = f2b(x - b2f(h));
    }
    qhi[ks] = th.b; qlo[ks] = tl.b;
  }

  f32x4 oacc[4] = { {0,0,0,0}, {0,0,0,0}, {0,0,0,0}, {0,0,0,0} };
  float m = 0.0f;                 // running max (base-2; sink pins m >= 0)
  f32x4 l4 = {0, 0, 0, 0};        // packed partial denominator

  const int ntiles = qt + 1;
  const size_t tbase = (size_t)bh * NT;

  // incrementally-advanced ws pointers (shaves address VALU in the loop)
  const char* Kp = (const char*)(wsK + tbase * 4096);
  const char* Vp = (const char*)(wsV + tbase * 4096);
  const char* Bp = (const char*)(wsB + tbase * 64);

  auto STAGE = [&](int buf) {
#pragma unroll
    for (int c = 0; c < 2; c++) {
      int boff = wid * 2048 + c * 1024;
      gl_lds16(Kp + boff + lane * 16, (char*)&sK[buf][0] + boff);
      gl_lds16(Vp + boff + lane * 16, (char*)&sV[buf][0] + boff);
    }
    if (wid == 0) gl_lds4(Bp + lane * 4, (char*)&sB[buf][0]);
  };

  int cur = 0;
  STAGE(0);
  Kp += 8192; Vp += 8192; Bp += 256;
  __syncthreads();

  for (int t = 0; t < ntiles; t++) {
    if (t + 1 < ntiles) {
      STAGE(cur ^ 1);
      Kp += 8192; Vp += 8192; Bp += 256;
    }

    // ---- QK^T, swapped: S^T = K . Q^T ----
    f32x4 sc[4] = { {0,0,0,0}, {0,0,0,0}, {0,0,0,0}, {0,0,0,0} };
#pragma unroll
    for (int c = 0; c < 4; c++) {
#pragma unroll
      for (int ks = 0; ks < 2; ks++) {
        int idx = (16 * c + qi) * 64 + ((ks * 32 + g * 8) ^ ((qi & 7) << 3));
        bf16x8 ak = *(const bf16x8*)&sK[cur][idx];
        sc[c] = __builtin_amdgcn_mfma_f32_16x16x32_bf16(ak, qhi[ks], sc[c], 0, 0, 0);
        sc[c] = __builtin_amdgcn_mfma_f32_16x16x32_bf16(ak, qlo[ks], sc[c], 0, 0, 0);
      }
    }

    // ---- softmax: s = sc + bias, causal mask on diag tile ----
    const bool diag = (t == ntiles - 1);
    const int tile64 = t * 64;
#pragma unroll
    for (int c = 0; c < 4; c++) {
      f32x4 bb = *(const f32x4*)&sB[cur][16 * c + 4 * g];
      sc[c] += bb;                              // v_pk_add_f32
      if (diag) {
#pragma unroll
        for (int r = 0; r < 4; r++) {
          int key = tile64 + 32 * (c >> 1) + 8 * g + 4 * (c & 1) + r; // pi(slot)
          if (key > qg) sc[c][r] = -1e30f;
        }
      }
    }

    // ---- exact defer-max: rescale only if some score exceeds running max ----
    f32x4 mv = vmax4(vmax4(sc[0], sc[1]), vmax4(sc[2], sc[3]));
    float mloc = fmaxf(fmaxf(fmaxf(mv[0], mv[1]), mv[2]), mv[3]); // v_max3 fuse
    if (!__all(mloc <= m)) {                    // ~never taken (sink pins m=0)
      float mt = fmaxf(mloc, __shfl_xor(mloc, 16, 64));
      mt = fmaxf(mt, __shfl_xor(mt, 32, 64));
      float dm = fmaxf(mt - m, 0.0f);           // per-query, exact
      m += dm;
      float alpha = exp2f(-dm);
      l4 *= alpha;
#pragma unroll
      for (int db = 0; db < 4; db++) oacc[db] *= alpha;
    }

    // ---- weights: e = exp2(s - m); m==0 fast path skips the subtract ----
    if (__all(m == 0.0f)) {
#pragma unroll
      for (int c = 0; c < 4; c++) {
#pragma unroll
        for (int r = 0; r < 4; r++) sc[c][r] = exp2f(sc[c][r]);
        l4 += sc[c];
      }
    } else {
#pragma unroll
      for (int c = 0; c < 4; c++) {
#pragma unroll
        for (int r = 0; r < 4; r++) sc[c][r] = exp2f(sc[c][r] - m);
        l4 += sc[c];
      }
    }

    // ---- P repack (local by slot-permutation construction) ----
    B8 t0, t1;
#pragma unroll
    for (int j = 0; j < 8; j++) {
      t0.b[j] = (__bf16)sc[(j >> 2)][j & 3];
      t1.b[j] = (__bf16)sc[2 + (j >> 2)][j & 3];
    }

    // ---- PV: O^T += V^T . P^T ----
#pragma unroll
    for (int db = 0; db < 4; db++) {
#pragma unroll
      for (int ks = 0; ks < 2; ks++) {
        int idx = (db * 16 + qi) * 64 + ((ks * 32 + g * 8) ^ ((qi & 7) << 3));
        bf16x8 av = *(const bf16x8*)&sV[cur][idx];
        oacc[db] = __builtin_amdgcn_mfma_f32_16x16x32_bf16(av, (ks ? t1.b : t0.b),
                                                           oacc[db], 0, 0, 0);
      }
    }
    __syncthreads();   // drains vmcnt (next tile landed) + LDS-read reuse fence
    cur ^= 1;
  }

  // ---- epilogue ----
  float lt = (l4[0] + l4[1]) + (l4[2] + l4[3]);
  lt += __shfl_xor(lt, 16, 64);
  lt += __shfl_xor(lt, 32, 64);
  float denom = lt + exp2f(-m);   // + sink weight
  float inv = 1.0f / denom;
  float* op = out + (bhN + qg) * DH;
#pragma unroll
  for (int db = 0; db < 4; db++) {
    float4 o;
    o.x = oacc[db][0] * inv;
    o.y = oacc[db][1] * inv;
    o.z = oacc[db][2] * inv;
    o.w = oacc[db][3] * inv;
    *(float4*)(op + db * 16 + 4 * g) = o;
  }
}

extern "C" void kernel_launch(void* const* d_in, const int* in_sizes, int n_in,
                              void* d_out, int out_size, void* d_ws, size_t ws_size,
                              hipStream_t stream) {
  (void)in_sizes; (void)n_in; (void)out_size; (void)ws_size;
  const float* q = (const float*)d_in[0];
  const float* k = (const float*)d_in[1];
  const float* v = (const float*)d_in[2];
  float* out = (float*)d_out;

  // ws layout: K images 8 MiB | V images 8 MiB | bias 256 KiB
  char* ws = (char*)d_ws;
  unsigned short* wsK = (unsigned short*)ws;
  unsigned short* wsV = (unsigned short*)(ws + (8u << 20));
  float*          wsB = (float*)(ws + (16u << 20));

  build_ws<<<dim3(32, NT), dim3(256), 0, stream>>>(k, v, wsK, wsV, wsB);
  attend_l2_flash<<<dim3(1024), dim3(256), 0, stream>>>(q, wsK, wsV, wsB, out);
}